// Round 4
// baseline (94.691 us; speedup 1.0000x reference)
//
#include <hip/hip_runtime.h>
#include <math.h>

#define TS 4
#define SDIM 128
#define PIX (SDIM * SDIM)
#define TEXW 512
#define TEXH 512
#define EPS 1e-9f
#define NCHUNK 32
#define NTILE 64  // 8x8 tiles of 16x16 pixels
#define MAXCF 128
#define BBOX_MARGIN 1e-3f

// ---- shared camera / transform helpers (bit-identical in both kernels) -----
__device__ __forceinline__ void camera_setup(const void* azi_p,
                                             const void* ele_p, float eye[3],
                                             float xv[3], float yv[3],
                                             float zv[3]) {
#pragma clang fp contract(off)
    // azi/ele are 1-element arrays; decode int-vs-float by bit pattern.
    int ai = *(const int*)azi_p;
    float az = (ai > -360000 && ai < 360000) ? (float)ai : *(const float*)azi_p;
    int ei = *(const int*)ele_p;
    float el = (ei > -360000 && ei < 360000) ? (float)ei : *(const float*)ele_p;
    float a = az * (float)(M_PI / 180.0);
    float e = el * (float)(M_PI / 180.0);
    float ca = cosf(a), sa = sinf(a);
    float ce = cosf(e), se = sinf(e);
    eye[0] = 2.732f * (ce * sa);
    eye[1] = 2.732f * se;
    eye[2] = 2.732f * ((-ce) * ca);
    float nrm = sqrtf(eye[0] * eye[0] + eye[1] * eye[1] + eye[2] * eye[2]);
    zv[0] = (-eye[0]) / nrm;
    zv[1] = (-eye[1]) / nrm;
    zv[2] = (-eye[2]) / nrm;
    // x = cross(up, z), up = (0,1,0)
    float cx0 = 1.0f * zv[2] - 0.0f * zv[1];
    float cx1 = 0.0f * zv[0] - 0.0f * zv[2];
    float cx2 = 0.0f * zv[1] - 1.0f * zv[0];
    float xn = sqrtf(cx0 * cx0 + cx1 * cx1 + cx2 * cx2);
    xv[0] = cx0 / xn; xv[1] = cx1 / xn; xv[2] = cx2 / xn;
    // y = cross(z, x), then normalize
    float cy0 = zv[1] * xv[2] - zv[2] * xv[1];
    float cy1 = zv[2] * xv[0] - zv[0] * xv[2];
    float cy2 = zv[0] * xv[1] - zv[1] * xv[0];
    float yn = sqrtf(cy0 * cy0 + cy1 * cy1 + cy2 * cy2);
    yv[0] = cy0 / yn; yv[1] = cy1 / yn; yv[2] = cy2 / yn;
}

__device__ __forceinline__ void face_transform(
    const float* __restrict__ verts, const int* __restrict__ faces, int f,
    const float eye[3], const float xv[3], const float yv[3],
    const float zv[3], float q[3][3]) {
#pragma clang fp contract(off)
    for (int k = 0; k < 3; ++k) {
        int vi = faces[f * 3 + k];
        float d0 = verts[vi * 3 + 0] - eye[0];
        float d1 = verts[vi * 3 + 1] - eye[1];
        float d2 = verts[vi * 3 + 2] - eye[2];
        q[k][0] = d0 * xv[0] + d1 * xv[1] + d2 * xv[2];
        q[k][1] = d0 * yv[0] + d1 * yv[1] + d2 * yv[2];
        q[k][2] = d0 * zv[0] + d1 * zv[1] + d2 * zv[2];
    }
}

// ---------------- Kernel 1: fused setup + tiled raster ----------------------
// grid = (NTILE, NCHUNK); block = 256 = one 16x16-pixel tile x one face chunk.
// Each block transforms its chunk's faces in-registers, bbox-culls vs its
// tile, compacts survivors into LDS, tests them, writes (depth,fid) partial.
__global__ void raster_kernel(const float* __restrict__ verts,
                              const int* __restrict__ faces,
                              const void* __restrict__ azi_p,
                              const void* __restrict__ ele_p,
                              uint2* __restrict__ partial, int F,
                              int chunkFaces) {
#pragma clang fp contract(off)
    __shared__ float4 sA[MAXCF];  // p0x p0y e1x e1y
    __shared__ float4 sB[MAXCF];  // e2x e2y inv fid(bits)
    __shared__ float4 sZ[MAXCF];  // z0 z1 z2 -
    __shared__ int cnt;
    if (threadIdx.x == 0) cnt = 0;
    __syncthreads();

    int tileX = blockIdx.x & 7, tileY = blockIdx.x >> 3;
    int chunk = blockIdx.y;
    int f0 = chunk * chunkFaces;
    // tile NDC bounds (pixel centers) with conservative margin
    float xlo = (tileX * 16 + 0.5f) / 64.0f - 1.0f - BBOX_MARGIN;
    float xhi = (tileX * 16 + 15.5f) / 64.0f - 1.0f + BBOX_MARGIN;
    float yhi = 1.0f - (tileY * 16 + 0.5f) / 64.0f + BBOX_MARGIN;
    float ylo = 1.0f - (tileY * 16 + 15.5f) / 64.0f - BBOX_MARGIN;

    float eye[3], xv[3], yv[3], zv[3];
    camera_setup(azi_p, ele_p, eye, xv, yv, zv);

    int k = threadIdx.x;
    int f = f0 + k;
    if (k < chunkFaces && k < MAXCF && f < F) {
        float q[3][3];
        face_transform(verts, faces, f, eye, xv, yv, zv, q);
        float e1x = q[1][0] - q[0][0], e1y = q[1][1] - q[0][1];
        float e2x = q[2][0] - q[0][0], e2y = q[2][1] - q[0][1];
        float det = e1x * e2y - e1y * e2x;
        bool valid = fabsf(det) > EPS;
        float inv = 1.0f / (valid ? det : 1.0f);
        // invalid det -> z=inf -> depth inf/NaN -> excluded by < INFINITY
        float z0 = valid ? q[0][2] : INFINITY;
        float z1 = valid ? q[1][2] : INFINITY;
        float z2 = valid ? q[2][2] : INFINITY;
        float p1x = q[0][0] + e1x, p1y = q[0][1] + e1y;
        float p2x = q[0][0] + e2x, p2y = q[0][1] + e2y;
        float bxmin = fminf(q[0][0], fminf(p1x, p2x));
        float bxmax = fmaxf(q[0][0], fmaxf(p1x, p2x));
        float bymin = fminf(q[0][1], fminf(p1y, p2y));
        float bymax = fmaxf(q[0][1], fmaxf(p1y, p2y));
        if (bxmin <= xhi && bxmax >= xlo && bymin <= yhi && bymax >= ylo) {
            int pos = atomicAdd(&cnt, 1);
            sA[pos] = make_float4(q[0][0], q[0][1], e1x, e1y);
            sB[pos] = make_float4(e2x, e2y, inv, __int_as_float(f));
            sZ[pos] = make_float4(z0, z1, z2, 0.0f);
        }
    }
    __syncthreads();
    int n = cnt;

    int j = tileX * 16 + (threadIdx.x & 15);
    int i = tileY * 16 + (threadIdx.x >> 4);
    float px = ((j + 0.5f) / 128.0f) * 2.0f - 1.0f;
    float py = 1.0f - ((i + 0.5f) / 128.0f) * 2.0f;
    float best = INFINITY;
    int bfid = 0x7fffffff;
    for (int s = 0; s < n; ++s) {
        float4 A = sA[s];
        float4 B = sB[s];
        float4 C = sZ[s];
        float dx = px - A.x, dy = py - A.y;
        float w1 = (dx * B.y - dy * B.x) * B.z;
        float w2 = (A.z * dy - A.w * dx) * B.z;
        float w0 = 1.0f - w1 - w2;
        bool inside = (w0 >= 0.0f) && (w1 >= 0.0f) && (w2 >= 0.0f);
        float depth = w0 * C.x + w1 * C.y + w2 * C.z;
        int fid = __float_as_int(B.w);
        // lexicographic (depth, fid): order-independent == first-min argmin
        if (inside && depth < INFINITY &&
            (depth < best || (depth == best && fid < bfid))) {
            best = depth;
            bfid = fid;
        }
    }
    partial[chunk * PIX + i * SDIM + j] =
        make_uint2(__float_as_uint(best), (unsigned int)bfid);
}

// ---------------- Kernel 2: combine + recompute winner + bilinear + write ---
__global__ void shade_kernel(const uint2* __restrict__ partial,
                             const float* __restrict__ verts,
                             const int* __restrict__ faces,
                             const void* __restrict__ azi_p,
                             const void* __restrict__ ele_p,
                             const float* __restrict__ img,
                             const float* __restrict__ grid,
                             float* __restrict__ out, int nChunks) {
#pragma clang fp contract(off)
    int t = blockIdx.x * 256 + threadIdx.x;
    int i = t >> 7, j = t & 127;
    int o = i * SDIM + (SDIM - 1 - j);  // x-flip ([..., ::-1])
    float best = INFINITY;
    int bfid = 0x7fffffff;
    for (int c = 0; c < nChunks; ++c) {
        uint2 P = partial[c * PIX + t];
        float d = __uint_as_float(P.x);
        int fid = (int)P.y;
        if (d < best || (d == best && fid < bfid)) {
            best = d;
            bfid = fid;
        }
    }
    if (!isfinite(best)) {  // no hit -> zeros (matches where(hit, col, 0))
        out[0 * PIX + o] = 0.0f;
        out[1 * PIX + o] = 0.0f;
        out[2 * PIX + o] = 0.0f;
        return;
    }
    // recompute winning face transform (bit-identical op sequence)
    float eye[3], xv[3], yv[3], zv[3];
    camera_setup(azi_p, ele_p, eye, xv, yv, zv);
    float q[3][3];
    face_transform(verts, faces, bfid, eye, xv, yv, zv, q);
    float e1x = q[1][0] - q[0][0], e1y = q[1][1] - q[0][1];
    float e2x = q[2][0] - q[0][0], e2y = q[2][1] - q[0][1];
    float det = e1x * e2y - e1y * e2x;
    float inv = 1.0f / (fabsf(det) > EPS ? det : 1.0f);
    float px = ((j + 0.5f) / 128.0f) * 2.0f - 1.0f;
    float py = 1.0f - ((i + 0.5f) / 128.0f) * 2.0f;
    float dx = px - q[0][0], dy = py - q[0][1];
    float w1 = (dx * e2y - dy * e2x) * inv;
    float w2 = (e1x * dy - e1y * dx) * inv;
    float w0 = 1.0f - w1 - w2;
    int i0 = min(max((int)floorf(w0 * (float)TS), 0), TS - 1);
    int i1 = min(max((int)floorf(w1 * (float)TS), 0), TS - 1);
    int i2 = min(max((int)floorf(w2 * (float)TS), 0), TS - 1);
    int sidx = bfid * (TS * TS * TS) + i0 * 16 + i1 * 4 + i2;
    // on-demand bilinear sample (bit-identical to reference grid_sample)
    float gx = grid[2 * sidx], gy = grid[2 * sidx + 1];
    float x = (gx + 1.0f) * (TEXW * 0.5f) - 0.5f;
    float y = (gy + 1.0f) * (TEXH * 0.5f) - 0.5f;
    float x0f = floorf(x), y0f = floorf(y);
    float tx = x - x0f, ty = y - y0f;
    int x0 = (int)x0f, y0 = (int)y0f;
    float w00 = (1.0f - tx) * (1.0f - ty);
    float w10 = tx * (1.0f - ty);
    float w01 = (1.0f - tx) * ty;
    float w11 = tx * ty;
    bool vx0 = (x0 >= 0) && (x0 < TEXW);
    bool vx1 = (x0 + 1 >= 0) && (x0 + 1 < TEXW);
    bool vy0 = (y0 >= 0) && (y0 < TEXH);
    bool vy1 = (y0 + 1 >= 0) && (y0 + 1 < TEXH);
    int xc0 = min(max(x0, 0), TEXW - 1);
    int xc1 = min(max(x0 + 1, 0), TEXW - 1);
    int yc0 = min(max(y0, 0), TEXH - 1);
    int yc1 = min(max(y0 + 1, 0), TEXH - 1);
    float W00 = (vx0 && vy0) ? w00 : 0.0f;
    float W10 = (vx1 && vy0) ? w10 : 0.0f;
    float W01 = (vx0 && vy1) ? w01 : 0.0f;
    float W11 = (vx1 && vy1) ? w11 : 0.0f;
    for (int c = 0; c < 3; ++c) {
        const float* ic = img + c * (TEXH * TEXW);
        float acc = ic[yc0 * TEXW + xc0] * W00;
        acc = acc + ic[yc0 * TEXW + xc1] * W10;
        acc = acc + ic[yc1 * TEXW + xc0] * W01;
        acc = acc + ic[yc1 * TEXW + xc1] * W11;
        out[c * PIX + o] = acc;
    }
}

extern "C" void kernel_launch(void* const* d_in, const int* in_sizes, int n_in,
                              void* d_out, int out_size, void* d_ws,
                              size_t ws_size, hipStream_t stream) {
    const float* verts = (const float*)d_in[0];
    const float* img = (const float*)d_in[1];
    const float* grid = (const float*)d_in[2];
    const int* faces = (const int*)d_in[3];
    const void* azi = d_in[4];
    const void* ele = d_in[5];
    float* out = (float*)d_out;

    int F = in_sizes[3] / 3;  // faces
    uint2* partial = (uint2*)d_ws;  // NCHUNK * PIX * 8 B = 4 MB

    int chunkFaces = (F + NCHUNK - 1) / NCHUNK;  // 63 for F=2000 (<= MAXCF)

    raster_kernel<<<dim3(NTILE, NCHUNK), 256, 0, stream>>>(
        verts, faces, azi, ele, partial, F, chunkFaces);
    shade_kernel<<<PIX / 256, 256, 0, stream>>>(partial, verts, faces, azi,
                                                ele, img, grid, out, NCHUNK);
}

// Round 5
// 86.310 us; speedup vs baseline: 1.0971x; 1.0971x over previous
//
#include <hip/hip_runtime.h>
#include <math.h>

#define TS 4
#define SDIM 128
#define PIX (SDIM * SDIM)
#define TEXW 512
#define TEXH 512
#define EPS 1e-9f
#define NCHUNK 32
#define NTILE 64  // 8x8 tiles of 16x16 pixels
#define MAXCF 128
#define BBOX_MARGIN 1e-3f

// ---------------- Kernel 1: face setup + zbuf init --------------------------
__device__ inline void cross3(const float a[3], const float b[3], float o[3]) {
    o[0] = a[1] * b[2] - a[2] * b[1];
    o[1] = a[2] * b[0] - a[0] * b[2];
    o[2] = a[0] * b[1] - a[1] * b[0];
}

__global__ void setup_kernel(const float* __restrict__ verts,
                             const int* __restrict__ faces,
                             const void* __restrict__ azi_p,
                             const void* __restrict__ ele_p,
                             float4* __restrict__ fd,
                             unsigned long long* __restrict__ zbuf,
                             int F, int faceBlocks) {
#pragma clang fp contract(off)
    if ((int)blockIdx.x >= faceBlocks) {
        int t = (blockIdx.x - faceBlocks) * 256 + threadIdx.x;
        if (t < PIX) zbuf[t] = ~0ull;
        return;
    }
    int f = blockIdx.x * 256 + threadIdx.x;
    if (f >= F) return;
    // azi/ele are 1-element arrays; decode int-vs-float by bit pattern.
    int ai = *(const int*)azi_p;
    float az = (ai > -360000 && ai < 360000) ? (float)ai : *(const float*)azi_p;
    int ei = *(const int*)ele_p;
    float el = (ei > -360000 && ei < 360000) ? (float)ei : *(const float*)ele_p;
    float a = az * (float)(M_PI / 180.0);
    float e = el * (float)(M_PI / 180.0);
    float ca = cosf(a), sa = sinf(a);
    float ce = cosf(e), se = sinf(e);
    float eye[3];
    eye[0] = 2.732f * (ce * sa);
    eye[1] = 2.732f * se;
    eye[2] = 2.732f * ((-ce) * ca);
    float nrm = sqrtf(eye[0] * eye[0] + eye[1] * eye[1] + eye[2] * eye[2]);
    float zv[3] = { (-eye[0]) / nrm, (-eye[1]) / nrm, (-eye[2]) / nrm };
    float up[3] = { 0.0f, 1.0f, 0.0f };
    float xv[3];
    cross3(up, zv, xv);
    float xn = sqrtf(xv[0] * xv[0] + xv[1] * xv[1] + xv[2] * xv[2]);
    xv[0] /= xn; xv[1] /= xn; xv[2] /= xn;
    float yv[3];
    cross3(zv, xv, yv);
    float yn = sqrtf(yv[0] * yv[0] + yv[1] * yv[1] + yv[2] * yv[2]);
    yv[0] /= yn; yv[1] /= yn; yv[2] /= yn;

    float q[3][3];
    for (int k = 0; k < 3; ++k) {
        int vi = faces[f * 3 + k];
        float d0 = verts[vi * 3 + 0] - eye[0];
        float d1 = verts[vi * 3 + 1] - eye[1];
        float d2 = verts[vi * 3 + 2] - eye[2];
        q[k][0] = d0 * xv[0] + d1 * xv[1] + d2 * xv[2];
        q[k][1] = d0 * yv[0] + d1 * yv[1] + d2 * yv[2];
        q[k][2] = d0 * zv[0] + d1 * zv[1] + d2 * zv[2];
    }
    float e1x = q[1][0] - q[0][0], e1y = q[1][1] - q[0][1];
    float e2x = q[2][0] - q[0][0], e2y = q[2][1] - q[0][1];
    float det = e1x * e2y - e1y * e2x;
    bool valid = fabsf(det) > EPS;
    float inv = 1.0f / (valid ? det : 1.0f);
    // invalid det -> z=inf so depth is inf/NaN -> never selected
    float z0 = valid ? q[0][2] : INFINITY;
    float z1 = valid ? q[1][2] : INFINITY;
    float z2 = valid ? q[2][2] : INFINITY;
    fd[f * 3 + 0] = make_float4(q[0][0], q[0][1], e1x, e1y);
    fd[f * 3 + 1] = make_float4(e2x, e2y, inv, 0.0f);
    fd[f * 3 + 2] = make_float4(z0, z1, z2, 0.0f);
}

// monotone float->uint encoding (works for any sign; NaN excluded by caller)
__device__ inline unsigned int enc_depth(float d) {
    unsigned int u = __float_as_uint(d);
    return (u & 0x80000000u) ? ~u : (u | 0x80000000u);
}

// ---------------- Kernel 2: tiled raster: bbox cull + LDS compaction --------
// grid = (NTILE, NCHUNK); block = 256 = one 16x16-pixel tile x one face chunk
__global__ void raster_kernel(const float4* __restrict__ fd, int F,
                              int chunkFaces,
                              unsigned long long* __restrict__ zbuf) {
#pragma clang fp contract(off)
    __shared__ float4 sA[MAXCF];  // p0x p0y e1x e1y
    __shared__ float4 sB[MAXCF];  // e2x e2y inv fid(bits)
    __shared__ float4 sZ[MAXCF];  // z0 z1 z2 -
    __shared__ int cnt;
    if (threadIdx.x == 0) cnt = 0;
    __syncthreads();

    int tileX = blockIdx.x & 7, tileY = blockIdx.x >> 3;
    int f0 = blockIdx.y * chunkFaces;
    // tile NDC bounds (pixel centers) with conservative margin
    float xlo = (tileX * 16 + 0.5f) / 64.0f - 1.0f - BBOX_MARGIN;
    float xhi = (tileX * 16 + 15.5f) / 64.0f - 1.0f + BBOX_MARGIN;
    float yhi = 1.0f - (tileY * 16 + 0.5f) / 64.0f + BBOX_MARGIN;
    float ylo = 1.0f - (tileY * 16 + 15.5f) / 64.0f - BBOX_MARGIN;

    int k = threadIdx.x;
    int f = f0 + k;
    if (k < chunkFaces && f < F) {
        float4 A = fd[f * 3 + 0];
        float4 B = fd[f * 3 + 1];
        float4 C = fd[f * 3 + 2];
        float p1x = A.x + A.z, p1y = A.y + A.w;
        float p2x = A.x + B.x, p2y = A.y + B.y;
        float bxmin = fminf(A.x, fminf(p1x, p2x));
        float bxmax = fmaxf(A.x, fmaxf(p1x, p2x));
        float bymin = fminf(A.y, fminf(p1y, p2y));
        float bymax = fmaxf(A.y, fmaxf(p1y, p2y));
        if (bxmin <= xhi && bxmax >= xlo && bymin <= yhi && bymax >= ylo) {
            int pos = atomicAdd(&cnt, 1);
            B.w = __int_as_float(f);
            sA[pos] = A;
            sB[pos] = B;
            sZ[pos] = C;
        }
    }
    __syncthreads();
    int n = cnt;
    if (n == 0) return;

    int j = tileX * 16 + (threadIdx.x & 15);
    int i = tileY * 16 + (threadIdx.x >> 4);
    float px = ((j + 0.5f) / 128.0f) * 2.0f - 1.0f;
    float py = 1.0f - ((i + 0.5f) / 128.0f) * 2.0f;
    float best = INFINITY;
    int bfid = 0x7fffffff;
    bool have = false;
    for (int s = 0; s < n; ++s) {
        float4 A = sA[s];
        float4 B = sB[s];
        float4 C = sZ[s];
        float dx = px - A.x, dy = py - A.y;
        float w1 = (dx * B.y - dy * B.x) * B.z;
        float w2 = (A.z * dy - A.w * dx) * B.z;
        float w0 = 1.0f - w1 - w2;
        bool inside = (w0 >= 0.0f) && (w1 >= 0.0f) && (w2 >= 0.0f);
        float depth = w0 * C.x + w1 * C.y + w2 * C.z;
        int fid = __float_as_int(B.w);
        // lexicographic (depth, fid): order-independent == first-min argmin
        if (inside && depth < INFINITY &&
            (depth < best || (depth == best && fid < bfid))) {
            best = depth;
            bfid = fid;
            have = true;
        }
    }
    if (have) {
        unsigned long long pack =
            ((unsigned long long)enc_depth(best) << 32) | (unsigned int)bfid;
        atomicMin(&zbuf[i * SDIM + j], pack);
    }
}

// ---------------- Kernel 3: shade (decode zbuf + on-demand bilinear) --------
__global__ void shade_kernel(const unsigned long long* __restrict__ zbuf,
                             const float4* __restrict__ fd,
                             const float* __restrict__ img,
                             const float* __restrict__ grid,
                             float* __restrict__ out) {
#pragma clang fp contract(off)
    int t = blockIdx.x * 256 + threadIdx.x;
    int i = t >> 7, j = t & 127;
    int o = i * SDIM + (SDIM - 1 - j);  // x-flip ([..., ::-1])
    unsigned long long pack = zbuf[t];
    if (pack == ~0ull) {  // no finite hit -> zeros (matches where(hit))
        out[0 * PIX + o] = 0.0f;
        out[1 * PIX + o] = 0.0f;
        out[2 * PIX + o] = 0.0f;
        return;
    }
    int bfid = (int)(unsigned int)(pack & 0xffffffffu);
    // recompute barycentrics for winning face (bit-identical exprs)
    float4 A = fd[bfid * 3 + 0];
    float4 B = fd[bfid * 3 + 1];
    float px = ((j + 0.5f) / 128.0f) * 2.0f - 1.0f;
    float py = 1.0f - ((i + 0.5f) / 128.0f) * 2.0f;
    float dx = px - A.x, dy = py - A.y;
    float w1 = (dx * B.y - dy * B.x) * B.z;
    float w2 = (A.z * dy - A.w * dx) * B.z;
    float w0 = 1.0f - w1 - w2;
    int i0 = min(max((int)floorf(w0 * (float)TS), 0), TS - 1);
    int i1 = min(max((int)floorf(w1 * (float)TS), 0), TS - 1);
    int i2 = min(max((int)floorf(w2 * (float)TS), 0), TS - 1);
    int sidx = bfid * (TS * TS * TS) + i0 * 16 + i1 * 4 + i2;
    // on-demand bilinear sample (bit-identical to reference grid_sample)
    float gx = grid[2 * sidx], gy = grid[2 * sidx + 1];
    float x = (gx + 1.0f) * (TEXW * 0.5f) - 0.5f;
    float y = (gy + 1.0f) * (TEXH * 0.5f) - 0.5f;
    float x0f = floorf(x), y0f = floorf(y);
    float tx = x - x0f, ty = y - y0f;
    int x0 = (int)x0f, y0 = (int)y0f;
    float w00 = (1.0f - tx) * (1.0f - ty);
    float w10 = tx * (1.0f - ty);
    float w01 = (1.0f - tx) * ty;
    float w11 = tx * ty;
    bool vx0 = (x0 >= 0) && (x0 < TEXW);
    bool vx1 = (x0 + 1 >= 0) && (x0 + 1 < TEXW);
    bool vy0 = (y0 >= 0) && (y0 < TEXH);
    bool vy1 = (y0 + 1 >= 0) && (y0 + 1 < TEXH);
    int xc0 = min(max(x0, 0), TEXW - 1);
    int xc1 = min(max(x0 + 1, 0), TEXW - 1);
    int yc0 = min(max(y0, 0), TEXH - 1);
    int yc1 = min(max(y0 + 1, 0), TEXH - 1);
    float W00 = (vx0 && vy0) ? w00 : 0.0f;
    float W10 = (vx1 && vy0) ? w10 : 0.0f;
    float W01 = (vx0 && vy1) ? w01 : 0.0f;
    float W11 = (vx1 && vy1) ? w11 : 0.0f;
    for (int c = 0; c < 3; ++c) {
        const float* ic = img + c * (TEXH * TEXW);
        float acc = ic[yc0 * TEXW + xc0] * W00;
        acc = acc + ic[yc0 * TEXW + xc1] * W10;
        acc = acc + ic[yc1 * TEXW + xc0] * W01;
        acc = acc + ic[yc1 * TEXW + xc1] * W11;
        out[c * PIX + o] = acc;
    }
}

extern "C" void kernel_launch(void* const* d_in, const int* in_sizes, int n_in,
                              void* d_out, int out_size, void* d_ws,
                              size_t ws_size, hipStream_t stream) {
    const float* verts = (const float*)d_in[0];
    const float* img = (const float*)d_in[1];
    const float* grid = (const float*)d_in[2];
    const int* faces = (const int*)d_in[3];
    const void* azi = d_in[4];
    const void* ele = d_in[5];
    float* out = (float*)d_out;

    int F = in_sizes[3] / 3;  // faces

    char* ws = (char*)d_ws;
    size_t off = 0;
    float4* fd = (float4*)(ws + off);
    off += ((size_t)F * 3 * 16 + 255) & ~(size_t)255;
    unsigned long long* zbuf = (unsigned long long*)(ws + off);

    int faceBlocks = (F + 255) / 256;
    int zBlocks = (PIX + 255) / 256;
    int chunkFaces = (F + NCHUNK - 1) / NCHUNK;  // 63 for F=2000 (<= MAXCF)

    setup_kernel<<<faceBlocks + zBlocks, 256, 0, stream>>>(
        verts, faces, azi, ele, fd, zbuf, F, faceBlocks);
    raster_kernel<<<dim3(NTILE, NCHUNK), 256, 0, stream>>>(fd, F, chunkFaces,
                                                           zbuf);
    shade_kernel<<<PIX / 256, 256, 0, stream>>>(zbuf, fd, img, grid, out);
}